// Round 9
// baseline (177.172 us; speedup 1.0000x reference)
//
#include <hip/hip_runtime.h>
#include <hip/hip_bf16.h>

typedef __attribute__((ext_vector_type(8))) __bf16 bf16x8;
typedef __attribute__((ext_vector_type(8))) unsigned short ushort8;
typedef __attribute__((ext_vector_type(4))) float floatx4;

#define N_NODES   20000
#define N_EDGES   320000
#define IN_DIM    128
#define HID       64
#define HEADS     4
#define NUM_GRAPHS 128
#define N_CLASSES 10
#define BCAP      128     // bucket slots/node; deg~Poisson(16), P(>128)~1e-60

// prep grid segmentation
#define NB_CONV   67      // (16384+640+10+255)/256  — W2t/Wcf/bcf only (W1t deleted)
#define NB_FILL   1250    // bucket fill
#define NB_GEMM1  313     // (N_NODES+63)/64

__device__ inline float cvt_load(const void* p, int i, int isb) {
    return isb ? __bfloat162float(((const __hip_bfloat16*)p)[i]) : ((const float*)p)[i];
}

__device__ inline unsigned short bf16bits(float v) {
    return __builtin_bit_cast(unsigned short, __float2bfloat16(v));
}

__device__ inline unsigned pack2(float a, float b) {
    return (unsigned)bf16bits(a) | ((unsigned)bf16bits(b) << 16);
}

__device__ inline floatx4 unpack4(uint2 u) {
    floatx4 f;
    f.x = __uint_as_float(u.x << 16);
    f.y = __uint_as_float(u.x & 0xffff0000u);
    f.z = __uint_as_float(u.y << 16);
    f.w = __uint_as_float(u.y & 0xffff0000u);
    return f;
}

// per-block dtype detect: same predicate as the original init block 0 (16KB scan, L2-hot)
__device__ inline int detect_bf16(const unsigned int* hw) {
    __shared__ int s_bad;
    if (threadIdx.x == 0) s_bad = 0;
    __syncthreads();
    int bad = 0;
    for (int i = threadIdx.x; i < 4096; i += 256) {
        float v = __uint_as_float(hw[i]);
        if (!(fabsf(v) <= 1e20f)) bad = 1;
    }
    if (bad) atomicOr(&s_bad, 1);
    __syncthreads();
    return s_bad;
}

// ---------- MEGA-PREP: convW+detect [0,67) | bucket-fill [67,1317) | GEMM1 [1317,1630) ----------
// gemm1 merged in (R8->R9): its 313 MFMA blocks co-schedule with the 1250 latency-bound
// fill blocks (independent work), deleting one dispatch boundary and hiding gemm1's time.
// gemm1 segment reads RAW W1 per-fragment (strided + identical RNE convert) -> no W1t race;
// it also runs its own detect -> no flag race. Conv block 0 still publishes *flag for poolclass.
__global__ __launch_bounds__(256) void prep_kernel(const void* W1, const void* W2,
                                                   const void* Wc, const void* bc,
                                                   unsigned short* W2t, float* Wcf, float* bcf,
                                                   const int* __restrict__ src,
                                                   const int* __restrict__ dst,
                                                   int* __restrict__ cnt, int* __restrict__ bucket,
                                                   const void* __restrict__ h_any,
                                                   unsigned short* __restrict__ ft1,
                                                   int* flag) {
    int b = blockIdx.x;
    const int n2 = HID * HEADS * HID;           // 16384
    const int n3 = HID * N_CLASSES;             // 640
    const int n4 = N_CLASSES;                   // 10
    if (b < NB_CONV) {
        int isb = detect_bf16((const unsigned int*)h_any);
        if (b == 0 && threadIdx.x == 0) *flag = isb;   // for poolclass output dtype
        int i = b * 256 + threadIdx.x;
        if (i < n2) {
            int k = i >> 6, n = i & 63;             // W2[k][n]
            W2t[n * 256 + k] = bf16bits(cvt_load(W2, i, isb));
        } else if (i < n2 + n3) {
            int j = i - n2;
            Wcf[j] = cvt_load(Wc, j, isb);
        } else if (i < n2 + n3 + n4) {
            int j = i - n2 - n3;
            bcf[j] = cvt_load(bc, j, isb);
        }
    } else if (b < NB_CONV + NB_FILL) {
        int e = (b - NB_CONV) * 256 + threadIdx.x;
        if (e < N_EDGES) {
            int d = dst[e];
            int pos = atomicAdd(&cnt[d], 1);
            if (pos < BCAP) bucket[d * BCAP + pos] = src[e];
        }
    } else {
        // ---- GEMM1 segment: ft1[M,256] = A[M,128] @ W1, B-frags from raw W1 ----
        int b2 = b - (NB_CONV + NB_FILL);
        int isb = detect_bf16((const unsigned int*)h_any);
        int wave = threadIdx.x >> 6;
        int lane = threadIdx.x & 63;
        int q = lane >> 4, r = lane & 15;
        int m0 = b2 * 64;
        int n0 = wave * 64;
        floatx4 acc[4][4] = {};
        const unsigned short* W1b = (const unsigned short*)W1;
        const float*          W1f = (const float*)W1;
        const unsigned short* Ab  = (const unsigned short*)h_any;
        const float*          Af  = (const float*)h_any;
#pragma unroll
        for (int kk = 0; kk < 4; ++kk) {
            // B fragments: W1[k][n], k = kk*32+q*8+j (j=0..7), n = n0+ni*16+r
            bf16x8 bfrag[4];
#pragma unroll
            for (int ni = 0; ni < 4; ++ni) {
                int n = n0 + ni * 16 + r;
                int k0 = kk * 32 + q * 8;
                ushort8 u;
                if (isb) {
#pragma unroll
                    for (int j = 0; j < 8; ++j) u[j] = W1b[(k0 + j) * 256 + n];
                } else {
#pragma unroll
                    for (int j = 0; j < 8; ++j) u[j] = bf16bits(W1f[(k0 + j) * 256 + n]);
                }
                bfrag[ni] = __builtin_bit_cast(bf16x8, u);
            }
            // A fragments
            bf16x8 afrag[4];
#pragma unroll
            for (int mi = 0; mi < 4; ++mi) {
                int row = m0 + mi * 16 + r;
                bf16x8 a = {};
                if (row < N_NODES) {
                    if (isb) {
                        a = *(const bf16x8*)(Ab + row * 128 + kk * 32 + q * 8);
                    } else {
                        const floatx4* p = (const floatx4*)(Af + row * 128 + kk * 32 + q * 8);
                        floatx4 f0 = p[0], f1 = p[1];
                        ushort8 u;
                        u[0] = bf16bits(f0.x); u[1] = bf16bits(f0.y);
                        u[2] = bf16bits(f0.z); u[3] = bf16bits(f0.w);
                        u[4] = bf16bits(f1.x); u[5] = bf16bits(f1.y);
                        u[6] = bf16bits(f1.z); u[7] = bf16bits(f1.w);
                        a = __builtin_bit_cast(bf16x8, u);
                    }
                }
                afrag[mi] = a;
            }
#pragma unroll
            for (int mi = 0; mi < 4; ++mi)
#pragma unroll
                for (int ni = 0; ni < 4; ++ni)
                    acc[mi][ni] = __builtin_amdgcn_mfma_f32_16x16x32_bf16(afrag[mi], bfrag[ni], acc[mi][ni], 0, 0, 0);
        }
#pragma unroll
        for (int mi = 0; mi < 4; ++mi)
#pragma unroll
            for (int rr = 0; rr < 4; ++rr) {
                int row = m0 + mi * 16 + q * 4 + rr;
                if (row < N_NODES) {
#pragma unroll
                    for (int ni = 0; ni < 4; ++ni)
                        ft1[row * 256 + n0 + ni * 16 + r] = bf16bits(acc[mi][ni][rr]);
                }
            }
    }
}

// ---------- FUSED attention H=4 + projection (gemm2): 8 dsts/block, 1 wave/dst ----------
// Phase 1: per-wave attention over incoming edges -> x1 row (bf16) in LDS.
// Phase 2: waves 0-3 run the exact gemm2 MFMA tile (A rows = 8 LDS rows, B = W2t).
// Measured: fusion saves ~8us (R6); 8-edge unroll NEUTRAL-to-worse (R7) -> keep 4-edge loop.
__global__ __launch_bounds__(512) void attn4proj_kernel(const unsigned short* __restrict__ ft,
                                                        const int* __restrict__ cnt,
                                                        const int* __restrict__ bucket,
                                                        const unsigned short* __restrict__ W2t,
                                                        unsigned short* __restrict__ ft2) {
    __shared__ unsigned short x1t[8][256];
    int w    = threadIdx.x >> 6;   // dst slot 0..7
    int lane = threadIdx.x & 63;
    int dstv = blockIdx.x * 8 + w;
    floatx4 hd = unpack4(*(const uint2*)(ft + dstv * 256 + lane * 4));
    int deg  = min(cnt[dstv], BCAP);
    int base = dstv * BCAP;
    float l = 0.f;
    floatx4 acc = {0.f, 0.f, 0.f, 0.f};
    int i0 = 0;
    for (; i0 + 4 <= deg; i0 += 4) {
        int sn0 = bucket[base + i0],     sn1 = bucket[base + i0 + 1];
        int sn2 = bucket[base + i0 + 2], sn3 = bucket[base + i0 + 3];
        uint2 r0 = *(const uint2*)(ft + sn0 * 256 + lane * 4);
        uint2 r1 = *(const uint2*)(ft + sn1 * 256 + lane * 4);
        uint2 r2 = *(const uint2*)(ft + sn2 * 256 + lane * 4);
        uint2 r3 = *(const uint2*)(ft + sn3 * 256 + lane * 4);
        floatx4 h0 = unpack4(r0), h1 = unpack4(r1), h2 = unpack4(r2), h3 = unpack4(r3);
        float p0 = h0.x * hd.x + h0.y * hd.y + h0.z * hd.z + h0.w * hd.w;
        float p1 = h1.x * hd.x + h1.y * hd.y + h1.z * hd.z + h1.w * hd.w;
        float p2 = h2.x * hd.x + h2.y * hd.y + h2.z * hd.z + h2.w * hd.w;
        float p3 = h3.x * hd.x + h3.y * hd.y + h3.z * hd.z + h3.w * hd.w;
        p0 += __shfl_xor(p0, 1); p1 += __shfl_xor(p1, 1); p2 += __shfl_xor(p2, 1); p3 += __shfl_xor(p3, 1);
        p0 += __shfl_xor(p0, 2); p1 += __shfl_xor(p1, 2); p2 += __shfl_xor(p2, 2); p3 += __shfl_xor(p3, 2);
        p0 += __shfl_xor(p0, 4); p1 += __shfl_xor(p1, 4); p2 += __shfl_xor(p2, 4); p3 += __shfl_xor(p3, 4);
        p0 += __shfl_xor(p0, 8); p1 += __shfl_xor(p1, 8); p2 += __shfl_xor(p2, 8); p3 += __shfl_xor(p3, 8);
        float w0 = __expf(p0 * 0.125f);
        float w1 = __expf(p1 * 0.125f);
        float w2 = __expf(p2 * 0.125f);
        float w3 = __expf(p3 * 0.125f);
        l += (w0 + w1) + (w2 + w3);
        acc.x += w0 * h0.x + w1 * h1.x + w2 * h2.x + w3 * h3.x;
        acc.y += w0 * h0.y + w1 * h1.y + w2 * h2.y + w3 * h3.y;
        acc.z += w0 * h0.z + w1 * h1.z + w2 * h2.z + w3 * h3.z;
        acc.w += w0 * h0.w + w1 * h1.w + w2 * h2.w + w3 * h3.w;
    }
    for (; i0 < deg; ++i0) {
        int sn = bucket[base + i0];
        floatx4 hs = unpack4(*(const uint2*)(ft + sn * 256 + lane * 4));
        float p = hs.x * hd.x + hs.y * hd.y + hs.z * hd.z + hs.w * hd.w;
        p += __shfl_xor(p, 1); p += __shfl_xor(p, 2);
        p += __shfl_xor(p, 4); p += __shfl_xor(p, 8);
        float wgt = __expf(p * 0.125f);
        l += wgt;
        acc.x += wgt * hs.x; acc.y += wgt * hs.y;
        acc.z += wgt * hs.z; acc.w += wgt * hs.w;
    }
    float inv = (l > 0.f) ? 1.f / l : 0.f;
    // x1 row (relu, bf16) -> LDS. lanes stride 8B -> 2-way bank alias (free).
    unsigned* xr = (unsigned*)&x1t[w][lane * 4];
    xr[0] = pack2(fmaxf(acc.x * inv, 0.f), fmaxf(acc.y * inv, 0.f));
    xr[1] = pack2(fmaxf(acc.z * inv, 0.f), fmaxf(acc.w * inv, 0.f));
    __syncthreads();
    // Phase 2: projection, identical MFMA structure to gemm2 (n0 = w*16)
    if (w < 4) {
        int q = lane >> 4, r = lane & 15;
        floatx4 pacc = {0.f, 0.f, 0.f, 0.f};
#pragma unroll
        for (int kk = 0; kk < 8; ++kk) {
            bf16x8 bfrag = *(const bf16x8*)(W2t + (w * 16 + r) * 256 + kk * 32 + q * 8);
            bf16x8 afrag = {};
            if (r < 8) afrag = *(const bf16x8*)(&x1t[r][kk * 32 + q * 8]);
            pacc = __builtin_amdgcn_mfma_f32_16x16x32_bf16(afrag, bfrag, pacc, 0, 0, 0);
        }
#pragma unroll
        for (int rr = 0; rr < 4; ++rr) {
            int row = q * 4 + rr;
            if (row < 8)
                ft2[(blockIdx.x * 8 + row) * 64 + w * 16 + r] = bf16bits(pacc[rr]);
        }
    }
}

// ---------- attention H=1 (proven, R1-measured): wave=dst, 4 groups, unroll-2 -> x2 f32 ----------
// NOTE: do NOT replace the x2 store with atomicAdd pooling — measured +38us regression (R4):
// device-scope f32 atomics write through to HBM (16B/atomic) and serialize at ~156-way/address.
__global__ __launch_bounds__(256) void attn_h1_kernel(const unsigned short* __restrict__ ft,
                                                      const int* __restrict__ cnt,
                                                      const int* __restrict__ bucket,
                                                      float* __restrict__ out) {
    int dstv = blockIdx.x * 4 + (threadIdx.x >> 6);
    int lane = threadIdx.x & 63;
    int g = lane >> 4, s = lane & 15;
    int hbase = s * 4;
    floatx4 hd = unpack4(*(const uint2*)(ft + dstv * 64 + hbase));
    int deg  = min(cnt[dstv], BCAP);
    int base = dstv * BCAP;
    float l = 0.f;
    floatx4 acc = {0.f, 0.f, 0.f, 0.f};
    int i0 = 0;
    for (; i0 + 8 <= deg; i0 += 8) {
        int ia = i0 + g, ib = i0 + 4 + g;
        int sa = bucket[base + ia], sb = bucket[base + ib];
        uint2 ra = *(const uint2*)(ft + sa * 64 + hbase);
        uint2 rb = *(const uint2*)(ft + sb * 64 + hbase);
        floatx4 ha = unpack4(ra), hb = unpack4(rb);
        float pa = ha.x * hd.x + ha.y * hd.y + ha.z * hd.z + ha.w * hd.w;
        float pb = hb.x * hd.x + hb.y * hd.y + hb.z * hd.z + hb.w * hd.w;
        pa += __shfl_xor(pa, 1); pb += __shfl_xor(pb, 1);
        pa += __shfl_xor(pa, 2); pb += __shfl_xor(pb, 2);
        pa += __shfl_xor(pa, 4); pb += __shfl_xor(pb, 4);
        pa += __shfl_xor(pa, 8); pb += __shfl_xor(pb, 8);
        float wa = __expf(pa * 0.125f);
        float wb = __expf(pb * 0.125f);
        l += wa + wb;
        acc.x += wa * ha.x + wb * hb.x;
        acc.y += wa * ha.y + wb * hb.y;
        acc.z += wa * ha.z + wb * hb.z;
        acc.w += wa * ha.w + wb * hb.w;
    }
    for (; i0 < deg; i0 += 4) {
        int i = i0 + g;
        bool valid = (i < deg);
        int sn = valid ? bucket[base + i] : 0;
        floatx4 hs = unpack4(*(const uint2*)(ft + sn * 64 + hbase));
        float p = hs.x * hd.x + hs.y * hd.y + hs.z * hd.z + hs.w * hd.w;
        p += __shfl_xor(p, 1); p += __shfl_xor(p, 2);
        p += __shfl_xor(p, 4); p += __shfl_xor(p, 8);
        float wgt = valid ? __expf(p * 0.125f) : 0.f;
        l += wgt;
        acc.x += wgt * hs.x; acc.y += wgt * hs.y;
        acc.z += wgt * hs.z; acc.w += wgt * hs.w;
    }
    l += __shfl_xor(l, 16); l += __shfl_xor(l, 32);
    acc.x += __shfl_xor(acc.x, 16); acc.x += __shfl_xor(acc.x, 32);
    acc.y += __shfl_xor(acc.y, 16); acc.y += __shfl_xor(acc.y, 32);
    acc.z += __shfl_xor(acc.z, 16); acc.z += __shfl_xor(acc.z, 32);
    acc.w += __shfl_xor(acc.w, 16); acc.w += __shfl_xor(acc.w, 32);
    float inv = (l > 0.f) ? 1.f / l : 0.f;
    if (g == 0) {
        floatx4 o = {fmaxf(acc.x * inv, 0.f), fmaxf(acc.y * inv, 0.f),
                     fmaxf(acc.z * inv, 0.f), fmaxf(acc.w * inv, 0.f)};
        *(floatx4*)(out + dstv * 64 + hbase) = o;
    }
}

// ---------- fused mean-pool + classifier (proven): 1 block / graph ----------
__global__ __launch_bounds__(256) void poolclass_kernel(const float* __restrict__ x,
                                                        const int* __restrict__ gid,
                                                        const float* __restrict__ Wc,
                                                        const float* __restrict__ bc,
                                                        void* out, const int* flag) {
    __shared__ int s_lo, s_hi;
    __shared__ float part[4][64];
    int g = blockIdx.x;
    int tid = threadIdx.x;
    if (tid == 0) {
        int lo = 0, hi = N_NODES;
        while (lo < hi) { int m = (lo + hi) >> 1; if (gid[m] < g) lo = m + 1; else hi = m; }
        s_lo = lo;
        int lo2 = lo, hi2 = N_NODES;
        while (lo2 < hi2) { int m = (lo2 + hi2) >> 1; if (gid[m] < g + 1) lo2 = m + 1; else hi2 = m; }
        s_hi = lo2;
    }
    __syncthreads();
    int lo = s_lo, hi = s_hi;
    int d = tid & 63, w = tid >> 6;
    float sum = 0.f;
    for (int n = lo + w; n < hi; n += 4) sum += x[n * 64 + d];
    part[w][d] = sum;
    __syncthreads();
    if (w == 0) {
        float tot = part[0][d] + part[1][d] + part[2][d] + part[3][d];
        int cntg = hi - lo;
        float mean = (cntg > 0) ? tot / (float)cntg : 0.f;
        for (int cls = 0; cls < N_CLASSES; ++cls) {
            float p = mean * Wc[d * N_CLASSES + cls];
#pragma unroll
            for (int o = 1; o < 64; o <<= 1) p += __shfl_xor(p, o);
            if (d == 0) {
                float r = p + bc[cls];
                if (*flag) ((__hip_bfloat16*)out)[g * N_CLASSES + cls] = __float2bfloat16(r);
                else       ((float*)out)[g * N_CLASSES + cls] = r;
            }
        }
    }
}

static inline size_t align256(size_t x) { return (x + 255) & ~size_t(255); }

extern "C" void kernel_launch(void* const* d_in, const int* in_sizes, int n_in,
                              void* d_out, int out_size, void* d_ws, size_t ws_size,
                              hipStream_t stream) {
    const void* h_raw  = d_in[0];
    const int*  src    = (const int*)d_in[1];
    const int*  dst    = (const int*)d_in[2];
    const int*  gid    = (const int*)d_in[3];
    const void* W1_raw = d_in[4];
    const void* W2_raw = d_in[5];
    const void* Wc_raw = d_in[6];
    const void* bc_raw = d_in[7];

    // ---- workspace layout (W1t deleted) ----
    char* w = (char*)d_ws;
    int*  flag     = (int*)w;                      w += 256;
    int*  cnt      = (int*)w;                      w += align256(N_NODES * 4);
    int*  bucket   = (int*)w;                      w += align256((size_t)N_NODES * BCAP * 4);  // 10.24MB
    unsigned short* W2t = (unsigned short*)w;      w += align256(64 * 256 * 2);
    float* Wcf     = (float*)w;                    w += align256(HID * N_CLASSES * 4);
    float* bcf     = (float*)w;                    w += 256;
    unsigned short* ft1  = (unsigned short*)w;     w += align256((size_t)N_NODES * 256 * 2);
    unsigned short* ft2  = (unsigned short*)w;     w += align256((size_t)N_NODES * HID * 2);
    float* x2      = (float*)w;                    w += align256((size_t)N_NODES * HID * 4);

    // 1) zero cnt via DMA memset node
    hipMemsetAsync(cnt, 0, N_NODES * sizeof(int), stream);

    // 2) MEGA-PREP: convW+detect (67) + bucket-fill (1250) + gemm1 (313) co-scheduled
    hipLaunchKernelGGL(prep_kernel, dim3(NB_CONV + NB_FILL + NB_GEMM1), dim3(256), 0, stream,
                       W1_raw, W2_raw, Wc_raw, bc_raw, W2t, Wcf, bcf,
                       src, dst, cnt, bucket,
                       h_raw, ft1, flag);

    // 3) FUSED attention layer 1 + W2 projection -> ft2  [8 dsts/block, 4-edge loop]
    hipLaunchKernelGGL(attn4proj_kernel, dim3(N_NODES / 8), dim3(512), 0, stream,
                       ft1, cnt, bucket, W2t, ft2);

    // 4) attention layer 2 -> x2 (f32, coalesced store — NOT atomics)
    hipLaunchKernelGGL(attn_h1_kernel, dim3(N_NODES / 4), dim3(256), 0, stream,
                       ft2, cnt, bucket, x2);

    // 5) fused mean-pool + classifier -> d_out
    hipLaunchKernelGGL(poolclass_kernel, dim3(NUM_GRAPHS), dim3(256), 0, stream,
                       x2, gid, Wcf, bcf, d_out, flag);
}

// Round 10
// 176.153 us; speedup vs baseline: 1.0058x; 1.0058x over previous
//
#include <hip/hip_runtime.h>
#include <hip/hip_bf16.h>

typedef __attribute__((ext_vector_type(8))) __bf16 bf16x8;
typedef __attribute__((ext_vector_type(8))) unsigned short ushort8;
typedef __attribute__((ext_vector_type(4))) float floatx4;

#define N_NODES   20000
#define N_EDGES   320000
#define IN_DIM    128
#define HID       64
#define HEADS     4
#define NUM_GRAPHS 128
#define N_CLASSES 10
#define BCAP      128     // bucket slots/node; deg~Poisson(16), P(>128)~1e-60

__device__ inline float cvt_load(const void* p, int i, int isb) {
    return isb ? __bfloat162float(((const __hip_bfloat16*)p)[i]) : ((const float*)p)[i];
}

__device__ inline unsigned short bf16bits(float v) {
    return __builtin_bit_cast(unsigned short, __float2bfloat16(v));
}

__device__ inline unsigned pack2(float a, float b) {
    return (unsigned)bf16bits(a) | ((unsigned)bf16bits(b) << 16);
}

__device__ inline floatx4 unpack4(uint2 u) {
    floatx4 f;
    f.x = __uint_as_float(u.x << 16);
    f.y = __uint_as_float(u.x & 0xffff0000u);
    f.z = __uint_as_float(u.y << 16);
    f.w = __uint_as_float(u.y & 0xffff0000u);
    return f;
}

// ---------- fused prep: convW [0,195) (with per-block dtype detect) | bucket-fill [195,1445) ----------
// R9 lesson: do NOT merge gemm1 in here — VGPR 80 for fill blocks + scalar W1 gather per
// gemm1 block measured +2us net and made prep the 46us top dispatch. Keep conv->W1t.
__global__ void prep_kernel(const void* W1, const void* W2, const void* Wc, const void* bc,
                            unsigned short* W1t, unsigned short* W2t, float* Wcf, float* bcf,
                            const int* __restrict__ src, const int* __restrict__ dst,
                            int* __restrict__ cnt, int* __restrict__ bucket,
                            const unsigned int* __restrict__ hw, int* flag) {
    int b = blockIdx.x;
    const int n1 = IN_DIM * HID * HEADS;        // 32768
    const int n2 = HID * HEADS * HID;           // 16384
    const int n3 = HID * N_CLASSES;             // 640
    const int n4 = N_CLASSES;                   // 10
    if (b < 195) {
        // per-block dtype detect (identical predicate to the original init block 0)
        __shared__ int s_bad;
        if (threadIdx.x == 0) s_bad = 0;
        __syncthreads();
        int bad = 0;
        for (int i = threadIdx.x; i < 4096; i += 256) {
            float v = __uint_as_float(hw[i]);
            if (!(fabsf(v) <= 1e20f)) bad = 1;
        }
        if (bad) atomicOr(&s_bad, 1);
        __syncthreads();
        int isb = s_bad;
        if (b == 0 && threadIdx.x == 0) *flag = isb;   // publish for gemm1/poolclass

        int i = b * 256 + threadIdx.x;
        if (i < n1) {
            int k = i >> 8, n = i & 255;            // W1[k][n]
            W1t[n * 128 + k] = bf16bits(cvt_load(W1, i, isb));
        } else if (i < n1 + n2) {
            int j = i - n1;
            int k = j >> 6, n = j & 63;             // W2[k][n]
            W2t[n * 256 + k] = bf16bits(cvt_load(W2, j, isb));
        } else if (i < n1 + n2 + n3) {
            int j = i - n1 - n2;
            Wcf[j] = cvt_load(Wc, j, isb);
        } else if (i < n1 + n2 + n3 + n4) {
            int j = i - n1 - n2 - n3;
            bcf[j] = cvt_load(bc, j, isb);
        }
    } else {
        int e = (b - 195) * 256 + threadIdx.x;
        if (e < N_EDGES) {
            int d = dst[e];
            int pos = atomicAdd(&cnt[d], 1);
            if (pos < BCAP) bucket[d * BCAP + pos] = src[e];
        }
    }
}

// ---------- GEMM1 (MFMA): ft1[M,256] = A[M,128] @ W1; A read directly (f32 or bf16) ----------
__global__ __launch_bounds__(256) void gemm1_kernel(const void* __restrict__ h_any,
                                                    const unsigned short* __restrict__ Bt,
                                                    unsigned short* __restrict__ C, int M,
                                                    const int* flag) {
    int wave = threadIdx.x >> 6;
    int lane = threadIdx.x & 63;
    int q = lane >> 4, r = lane & 15;
    int m0 = blockIdx.x * 64;
    int n0 = wave * 64;
    floatx4 acc[4][4] = {};
    bf16x8 bfrag[4][4];
#pragma unroll
    for (int ni = 0; ni < 4; ++ni)
#pragma unroll
        for (int kk = 0; kk < 4; ++kk)
            bfrag[ni][kk] = *(const bf16x8*)(Bt + (n0 + ni * 16 + r) * 128 + kk * 32 + q * 8);
    if (*flag) {
        const unsigned short* A = (const unsigned short*)h_any;
#pragma unroll
        for (int kk = 0; kk < 4; ++kk) {
            bf16x8 afrag[4];
#pragma unroll
            for (int mi = 0; mi < 4; ++mi) {
                int row = m0 + mi * 16 + r;
                bf16x8 a = {};
                if (row < M) a = *(const bf16x8*)(A + row * 128 + kk * 32 + q * 8);
                afrag[mi] = a;
            }
#pragma unroll
            for (int mi = 0; mi < 4; ++mi)
#pragma unroll
                for (int ni = 0; ni < 4; ++ni)
                    acc[mi][ni] = __builtin_amdgcn_mfma_f32_16x16x32_bf16(afrag[mi], bfrag[ni][kk], acc[mi][ni], 0, 0, 0);
        }
    } else {
        const float* A = (const float*)h_any;
#pragma unroll
        for (int kk = 0; kk < 4; ++kk) {
            bf16x8 afrag[4];
#pragma unroll
            for (int mi = 0; mi < 4; ++mi) {
                int row = m0 + mi * 16 + r;
                bf16x8 a = {};
                if (row < M) {
                    const floatx4* p = (const floatx4*)(A + row * 128 + kk * 32 + q * 8);
                    floatx4 f0 = p[0], f1 = p[1];
                    ushort8 u;
                    u[0] = bf16bits(f0.x); u[1] = bf16bits(f0.y);
                    u[2] = bf16bits(f0.z); u[3] = bf16bits(f0.w);
                    u[4] = bf16bits(f1.x); u[5] = bf16bits(f1.y);
                    u[6] = bf16bits(f1.z); u[7] = bf16bits(f1.w);
                    a = __builtin_bit_cast(bf16x8, u);
                }
                afrag[mi] = a;
            }
#pragma unroll
            for (int mi = 0; mi < 4; ++mi)
#pragma unroll
                for (int ni = 0; ni < 4; ++ni)
                    acc[mi][ni] = __builtin_amdgcn_mfma_f32_16x16x32_bf16(afrag[mi], bfrag[ni][kk], acc[mi][ni], 0, 0, 0);
        }
    }
#pragma unroll
    for (int mi = 0; mi < 4; ++mi)
#pragma unroll
        for (int rr = 0; rr < 4; ++rr) {
            int row = m0 + mi * 16 + q * 4 + rr;
            if (row < M) {
#pragma unroll
                for (int ni = 0; ni < 4; ++ni)
                    C[row * 256 + n0 + ni * 16 + r] = bf16bits(acc[mi][ni][rr]);
            }
        }
}

// ---------- FUSED attention H=4 + projection (gemm2): 8 dsts/block, 1 wave/dst ----------
// Phase 1: per-wave attention over incoming edges -> x1 row (bf16) in LDS.
// Phase 2: waves 0-3 run the exact gemm2 MFMA tile (A rows = 8 LDS rows, B = W2t).
// Measured: fusion saves ~8us (R6); 8-edge unroll NEUTRAL-to-worse (R7) -> keep 4-edge loop.
__global__ __launch_bounds__(512) void attn4proj_kernel(const unsigned short* __restrict__ ft,
                                                        const int* __restrict__ cnt,
                                                        const int* __restrict__ bucket,
                                                        const unsigned short* __restrict__ W2t,
                                                        unsigned short* __restrict__ ft2) {
    __shared__ unsigned short x1t[8][256];
    int w    = threadIdx.x >> 6;   // dst slot 0..7
    int lane = threadIdx.x & 63;
    int dstv = blockIdx.x * 8 + w;
    floatx4 hd = unpack4(*(const uint2*)(ft + dstv * 256 + lane * 4));
    int deg  = min(cnt[dstv], BCAP);
    int base = dstv * BCAP;
    float l = 0.f;
    floatx4 acc = {0.f, 0.f, 0.f, 0.f};
    int i0 = 0;
    for (; i0 + 4 <= deg; i0 += 4) {
        int sn0 = bucket[base + i0],     sn1 = bucket[base + i0 + 1];
        int sn2 = bucket[base + i0 + 2], sn3 = bucket[base + i0 + 3];
        uint2 r0 = *(const uint2*)(ft + sn0 * 256 + lane * 4);
        uint2 r1 = *(const uint2*)(ft + sn1 * 256 + lane * 4);
        uint2 r2 = *(const uint2*)(ft + sn2 * 256 + lane * 4);
        uint2 r3 = *(const uint2*)(ft + sn3 * 256 + lane * 4);
        floatx4 h0 = unpack4(r0), h1 = unpack4(r1), h2 = unpack4(r2), h3 = unpack4(r3);
        float p0 = h0.x * hd.x + h0.y * hd.y + h0.z * hd.z + h0.w * hd.w;
        float p1 = h1.x * hd.x + h1.y * hd.y + h1.z * hd.z + h1.w * hd.w;
        float p2 = h2.x * hd.x + h2.y * hd.y + h2.z * hd.z + h2.w * hd.w;
        float p3 = h3.x * hd.x + h3.y * hd.y + h3.z * hd.z + h3.w * hd.w;
        p0 += __shfl_xor(p0, 1); p1 += __shfl_xor(p1, 1); p2 += __shfl_xor(p2, 1); p3 += __shfl_xor(p3, 1);
        p0 += __shfl_xor(p0, 2); p1 += __shfl_xor(p1, 2); p2 += __shfl_xor(p2, 2); p3 += __shfl_xor(p3, 2);
        p0 += __shfl_xor(p0, 4); p1 += __shfl_xor(p1, 4); p2 += __shfl_xor(p2, 4); p3 += __shfl_xor(p3, 4);
        p0 += __shfl_xor(p0, 8); p1 += __shfl_xor(p1, 8); p2 += __shfl_xor(p2, 8); p3 += __shfl_xor(p3, 8);
        float w0 = __expf(p0 * 0.125f);
        float w1 = __expf(p1 * 0.125f);
        float w2 = __expf(p2 * 0.125f);
        float w3 = __expf(p3 * 0.125f);
        l += (w0 + w1) + (w2 + w3);
        acc.x += w0 * h0.x + w1 * h1.x + w2 * h2.x + w3 * h3.x;
        acc.y += w0 * h0.y + w1 * h1.y + w2 * h2.y + w3 * h3.y;
        acc.z += w0 * h0.z + w1 * h1.z + w2 * h2.z + w3 * h3.z;
        acc.w += w0 * h0.w + w1 * h1.w + w2 * h2.w + w3 * h3.w;
    }
    for (; i0 < deg; ++i0) {
        int sn = bucket[base + i0];
        floatx4 hs = unpack4(*(const uint2*)(ft + sn * 256 + lane * 4));
        float p = hs.x * hd.x + hs.y * hd.y + hs.z * hd.z + hs.w * hd.w;
        p += __shfl_xor(p, 1); p += __shfl_xor(p, 2);
        p += __shfl_xor(p, 4); p += __shfl_xor(p, 8);
        float wgt = __expf(p * 0.125f);
        l += wgt;
        acc.x += wgt * hs.x; acc.y += wgt * hs.y;
        acc.z += wgt * hs.z; acc.w += wgt * hs.w;
    }
    float inv = (l > 0.f) ? 1.f / l : 0.f;
    // x1 row (relu, bf16) -> LDS. lanes stride 8B -> 2-way bank alias (free).
    unsigned* xr = (unsigned*)&x1t[w][lane * 4];
    xr[0] = pack2(fmaxf(acc.x * inv, 0.f), fmaxf(acc.y * inv, 0.f));
    xr[1] = pack2(fmaxf(acc.z * inv, 0.f), fmaxf(acc.w * inv, 0.f));
    __syncthreads();
    // Phase 2: projection, identical MFMA structure to gemm2 (n0 = w*16)
    if (w < 4) {
        int q = lane >> 4, r = lane & 15;
        floatx4 pacc = {0.f, 0.f, 0.f, 0.f};
#pragma unroll
        for (int kk = 0; kk < 8; ++kk) {
            bf16x8 bfrag = *(const bf16x8*)(W2t + (w * 16 + r) * 256 + kk * 32 + q * 8);
            bf16x8 afrag = {};
            if (r < 8) afrag = *(const bf16x8*)(&x1t[r][kk * 32 + q * 8]);
            pacc = __builtin_amdgcn_mfma_f32_16x16x32_bf16(afrag, bfrag, pacc, 0, 0, 0);
        }
#pragma unroll
        for (int rr = 0; rr < 4; ++rr) {
            int row = q * 4 + rr;
            if (row < 8)
                ft2[(blockIdx.x * 8 + row) * 64 + w * 16 + r] = bf16bits(pacc[rr]);
        }
    }
}

// ---------- attention H=1 (proven, R1-measured): wave=dst, 4 groups, unroll-2 -> x2 f32 ----------
// NOTE: do NOT replace the x2 store with atomicAdd pooling — measured +38us regression (R4):
// device-scope f32 atomics write through to HBM (16B/atomic) and serialize at ~156-way/address.
__global__ __launch_bounds__(256) void attn_h1_kernel(const unsigned short* __restrict__ ft,
                                                      const int* __restrict__ cnt,
                                                      const int* __restrict__ bucket,
                                                      float* __restrict__ out) {
    int dstv = blockIdx.x * 4 + (threadIdx.x >> 6);
    int lane = threadIdx.x & 63;
    int g = lane >> 4, s = lane & 15;
    int hbase = s * 4;
    floatx4 hd = unpack4(*(const uint2*)(ft + dstv * 64 + hbase));
    int deg  = min(cnt[dstv], BCAP);
    int base = dstv * BCAP;
    float l = 0.f;
    floatx4 acc = {0.f, 0.f, 0.f, 0.f};
    int i0 = 0;
    for (; i0 + 8 <= deg; i0 += 8) {
        int ia = i0 + g, ib = i0 + 4 + g;
        int sa = bucket[base + ia], sb = bucket[base + ib];
        uint2 ra = *(const uint2*)(ft + sa * 64 + hbase);
        uint2 rb = *(const uint2*)(ft + sb * 64 + hbase);
        floatx4 ha = unpack4(ra), hb = unpack4(rb);
        float pa = ha.x * hd.x + ha.y * hd.y + ha.z * hd.z + ha.w * hd.w;
        float pb = hb.x * hd.x + hb.y * hd.y + hb.z * hd.z + hb.w * hd.w;
        pa += __shfl_xor(pa, 1); pb += __shfl_xor(pb, 1);
        pa += __shfl_xor(pa, 2); pb += __shfl_xor(pb, 2);
        pa += __shfl_xor(pa, 4); pb += __shfl_xor(pb, 4);
        pa += __shfl_xor(pa, 8); pb += __shfl_xor(pb, 8);
        float wa = __expf(pa * 0.125f);
        float wb = __expf(pb * 0.125f);
        l += wa + wb;
        acc.x += wa * ha.x + wb * hb.x;
        acc.y += wa * ha.y + wb * hb.y;
        acc.z += wa * ha.z + wb * hb.z;
        acc.w += wa * ha.w + wb * hb.w;
    }
    for (; i0 < deg; i0 += 4) {
        int i = i0 + g;
        bool valid = (i < deg);
        int sn = valid ? bucket[base + i] : 0;
        floatx4 hs = unpack4(*(const uint2*)(ft + sn * 64 + hbase));
        float p = hs.x * hd.x + hs.y * hd.y + hs.z * hd.z + hs.w * hd.w;
        p += __shfl_xor(p, 1); p += __shfl_xor(p, 2);
        p += __shfl_xor(p, 4); p += __shfl_xor(p, 8);
        float wgt = valid ? __expf(p * 0.125f) : 0.f;
        l += wgt;
        acc.x += wgt * hs.x; acc.y += wgt * hs.y;
        acc.z += wgt * hs.z; acc.w += wgt * hs.w;
    }
    l += __shfl_xor(l, 16); l += __shfl_xor(l, 32);
    acc.x += __shfl_xor(acc.x, 16); acc.x += __shfl_xor(acc.x, 32);
    acc.y += __shfl_xor(acc.y, 16); acc.y += __shfl_xor(acc.y, 32);
    acc.z += __shfl_xor(acc.z, 16); acc.z += __shfl_xor(acc.z, 32);
    acc.w += __shfl_xor(acc.w, 16); acc.w += __shfl_xor(acc.w, 32);
    float inv = (l > 0.f) ? 1.f / l : 0.f;
    if (g == 0) {
        floatx4 o = {fmaxf(acc.x * inv, 0.f), fmaxf(acc.y * inv, 0.f),
                     fmaxf(acc.z * inv, 0.f), fmaxf(acc.w * inv, 0.f)};
        *(floatx4*)(out + dstv * 64 + hbase) = o;
    }
}

// ---------- fused mean-pool + classifier (proven): 1 block / graph ----------
__global__ __launch_bounds__(256) void poolclass_kernel(const float* __restrict__ x,
                                                        const int* __restrict__ gid,
                                                        const float* __restrict__ Wc,
                                                        const float* __restrict__ bc,
                                                        void* out, const int* flag) {
    __shared__ int s_lo, s_hi;
    __shared__ float part[4][64];
    int g = blockIdx.x;
    int tid = threadIdx.x;
    if (tid == 0) {
        int lo = 0, hi = N_NODES;
        while (lo < hi) { int m = (lo + hi) >> 1; if (gid[m] < g) lo = m + 1; else hi = m; }
        s_lo = lo;
        int lo2 = lo, hi2 = N_NODES;
        while (lo2 < hi2) { int m = (lo2 + hi2) >> 1; if (gid[m] < g + 1) lo2 = m + 1; else hi2 = m; }
        s_hi = lo2;
    }
    __syncthreads();
    int lo = s_lo, hi = s_hi;
    int d = tid & 63, w = tid >> 6;
    float sum = 0.f;
    for (int n = lo + w; n < hi; n += 4) sum += x[n * 64 + d];
    part[w][d] = sum;
    __syncthreads();
    if (w == 0) {
        float tot = part[0][d] + part[1][d] + part[2][d] + part[3][d];
        int cntg = hi - lo;
        float mean = (cntg > 0) ? tot / (float)cntg : 0.f;
        for (int cls = 0; cls < N_CLASSES; ++cls) {
            float p = mean * Wc[d * N_CLASSES + cls];
#pragma unroll
            for (int o = 1; o < 64; o <<= 1) p += __shfl_xor(p, o);
            if (d == 0) {
                float r = p + bc[cls];
                if (*flag) ((__hip_bfloat16*)out)[g * N_CLASSES + cls] = __float2bfloat16(r);
                else       ((float*)out)[g * N_CLASSES + cls] = r;
            }
        }
    }
}

static inline size_t align256(size_t x) { return (x + 255) & ~size_t(255); }

extern "C" void kernel_launch(void* const* d_in, const int* in_sizes, int n_in,
                              void* d_out, int out_size, void* d_ws, size_t ws_size,
                              hipStream_t stream) {
    const void* h_raw  = d_in[0];
    const int*  src    = (const int*)d_in[1];
    const int*  dst    = (const int*)d_in[2];
    const int*  gid    = (const int*)d_in[3];
    const void* W1_raw = d_in[4];
    const void* W2_raw = d_in[5];
    const void* Wc_raw = d_in[6];
    const void* bc_raw = d_in[7];

    // ---- workspace layout ----
    char* w = (char*)d_ws;
    int*  flag     = (int*)w;                      w += 256;
    int*  cnt      = (int*)w;                      w += align256(N_NODES * 4);
    int*  bucket   = (int*)w;                      w += align256((size_t)N_NODES * BCAP * 4);  // 10.24MB
    unsigned short* W1t = (unsigned short*)w;      w += align256(256 * 128 * 2);
    unsigned short* W2t = (unsigned short*)w;      w += align256(64 * 256 * 2);
    float* Wcf     = (float*)w;                    w += align256(HID * N_CLASSES * 4);
    float* bcf     = (float*)w;                    w += 256;
    unsigned short* ft1  = (unsigned short*)w;     w += align256((size_t)N_NODES * 256 * 2);
    unsigned short* ft2  = (unsigned short*)w;     w += align256((size_t)N_NODES * HID * 2);
    float* x2      = (float*)w;                    w += align256((size_t)N_NODES * HID * 4);

    // 1) zero cnt via DMA memset node
    hipMemsetAsync(cnt, 0, N_NODES * sizeof(int), stream);

    // 2) fused prep: convW+detect (195) + bucket-fill (1250)
    hipLaunchKernelGGL(prep_kernel, dim3(195 + 1250), dim3(256), 0, stream,
                       W1_raw, W2_raw, Wc_raw, bc_raw, W1t, W2t, Wcf, bcf,
                       src, dst, cnt, bucket,
                       (const unsigned int*)h_raw, flag);

    // 3) layer 1 GEMM (MFMA), reads h directly in either dtype
    hipLaunchKernelGGL(gemm1_kernel, dim3((N_NODES + 63) / 64), dim3(256), 0, stream,
                       h_raw, W1t, ft1, N_NODES, flag);

    // 4) FUSED attention layer 1 + W2 projection -> ft2  [8 dsts/block, 4-edge loop]
    hipLaunchKernelGGL(attn4proj_kernel, dim3(N_NODES / 8), dim3(512), 0, stream,
                       ft1, cnt, bucket, W2t, ft2);

    // 5) attention layer 2 -> x2 (f32, coalesced store — NOT atomics)
    hipLaunchKernelGGL(attn_h1_kernel, dim3(N_NODES / 4), dim3(256), 0, stream,
                       ft2, cnt, bucket, x2);

    // 6) fused mean-pool + classifier -> d_out
    hipLaunchKernelGGL(poolclass_kernel, dim3(NUM_GRAPHS), dim3(256), 0, stream,
                       x2, gid, Wcf, bcf, d_out, flag);
}

// Round 11
// 175.058 us; speedup vs baseline: 1.0121x; 1.0063x over previous
//
#include <hip/hip_runtime.h>
#include <hip/hip_bf16.h>

typedef __attribute__((ext_vector_type(8))) __bf16 bf16x8;
typedef __attribute__((ext_vector_type(8))) unsigned short ushort8;
typedef __attribute__((ext_vector_type(4))) float floatx4;

#define N_NODES   20000
#define N_EDGES   320000
#define IN_DIM    128
#define HID       64
#define HEADS     4
#define NUM_GRAPHS 128
#define N_CLASSES 10
#define BCAP      128     // bucket slots/node; deg~Poisson(16), P(>128)~1e-60

__device__ inline float cvt_load(const void* p, int i, int isb) {
    return isb ? __bfloat162float(((const __hip_bfloat16*)p)[i]) : ((const float*)p)[i];
}

__device__ inline unsigned short bf16bits(float v) {
    return __builtin_bit_cast(unsigned short, __float2bfloat16(v));
}

__device__ inline unsigned pack2(float a, float b) {
    return (unsigned)bf16bits(a) | ((unsigned)bf16bits(b) << 16);
}

__device__ inline floatx4 unpack4(uint2 u) {
    floatx4 f;
    f.x = __uint_as_float(u.x << 16);
    f.y = __uint_as_float(u.x & 0xffff0000u);
    f.z = __uint_as_float(u.y << 16);
    f.w = __uint_as_float(u.y & 0xffff0000u);
    return f;
}

// ---------- fused prep: convW [0,195) (with per-block dtype detect) | bucket-fill [195,1445) ----------
// R9 lesson: do NOT merge gemm1 in here. R11: bucket is ushort (src<20000<65536) — halves the
// scattered-store write amplification and the bucket footprint (10.24->5.12MB), freeing L2 for ft1.
__global__ void prep_kernel(const void* W1, const void* W2, const void* Wc, const void* bc,
                            unsigned short* W1t, unsigned short* W2t, float* Wcf, float* bcf,
                            const int* __restrict__ src, const int* __restrict__ dst,
                            int* __restrict__ cnt, unsigned short* __restrict__ bucket,
                            const unsigned int* __restrict__ hw, int* flag) {
    int b = blockIdx.x;
    const int n1 = IN_DIM * HID * HEADS;        // 32768
    const int n2 = HID * HEADS * HID;           // 16384
    const int n3 = HID * N_CLASSES;             // 640
    const int n4 = N_CLASSES;                   // 10
    if (b < 195) {
        // per-block dtype detect (identical predicate to the original init block 0)
        __shared__ int s_bad;
        if (threadIdx.x == 0) s_bad = 0;
        __syncthreads();
        int bad = 0;
        for (int i = threadIdx.x; i < 4096; i += 256) {
            float v = __uint_as_float(hw[i]);
            if (!(fabsf(v) <= 1e20f)) bad = 1;
        }
        if (bad) atomicOr(&s_bad, 1);
        __syncthreads();
        int isb = s_bad;
        if (b == 0 && threadIdx.x == 0) *flag = isb;   // publish for gemm1/poolclass

        int i = b * 256 + threadIdx.x;
        if (i < n1) {
            int k = i >> 8, n = i & 255;            // W1[k][n]
            W1t[n * 128 + k] = bf16bits(cvt_load(W1, i, isb));
        } else if (i < n1 + n2) {
            int j = i - n1;
            int k = j >> 6, n = j & 63;             // W2[k][n]
            W2t[n * 256 + k] = bf16bits(cvt_load(W2, j, isb));
        } else if (i < n1 + n2 + n3) {
            int j = i - n1 - n2;
            Wcf[j] = cvt_load(Wc, j, isb);
        } else if (i < n1 + n2 + n3 + n4) {
            int j = i - n1 - n2 - n3;
            bcf[j] = cvt_load(bc, j, isb);
        }
    } else {
        int e = (b - 195) * 256 + threadIdx.x;
        if (e < N_EDGES) {
            int d = dst[e];
            int pos = atomicAdd(&cnt[d], 1);
            if (pos < BCAP) bucket[d * BCAP + pos] = (unsigned short)src[e];
        }
    }
}

// ---------- GEMM1 (MFMA): ft1[M,256] = A[M,128] @ W1; A read directly (f32 or bf16) ----------
__global__ __launch_bounds__(256) void gemm1_kernel(const void* __restrict__ h_any,
                                                    const unsigned short* __restrict__ Bt,
                                                    unsigned short* __restrict__ C, int M,
                                                    const int* flag) {
    int wave = threadIdx.x >> 6;
    int lane = threadIdx.x & 63;
    int q = lane >> 4, r = lane & 15;
    int m0 = blockIdx.x * 64;
    int n0 = wave * 64;
    floatx4 acc[4][4] = {};
    bf16x8 bfrag[4][4];
#pragma unroll
    for (int ni = 0; ni < 4; ++ni)
#pragma unroll
        for (int kk = 0; kk < 4; ++kk)
            bfrag[ni][kk] = *(const bf16x8*)(Bt + (n0 + ni * 16 + r) * 128 + kk * 32 + q * 8);
    if (*flag) {
        const unsigned short* A = (const unsigned short*)h_any;
#pragma unroll
        for (int kk = 0; kk < 4; ++kk) {
            bf16x8 afrag[4];
#pragma unroll
            for (int mi = 0; mi < 4; ++mi) {
                int row = m0 + mi * 16 + r;
                bf16x8 a = {};
                if (row < M) a = *(const bf16x8*)(A + row * 128 + kk * 32 + q * 8);
                afrag[mi] = a;
            }
#pragma unroll
            for (int mi = 0; mi < 4; ++mi)
#pragma unroll
                for (int ni = 0; ni < 4; ++ni)
                    acc[mi][ni] = __builtin_amdgcn_mfma_f32_16x16x32_bf16(afrag[mi], bfrag[ni][kk], acc[mi][ni], 0, 0, 0);
        }
    } else {
        const float* A = (const float*)h_any;
#pragma unroll
        for (int kk = 0; kk < 4; ++kk) {
            bf16x8 afrag[4];
#pragma unroll
            for (int mi = 0; mi < 4; ++mi) {
                int row = m0 + mi * 16 + r;
                bf16x8 a = {};
                if (row < M) {
                    const floatx4* p = (const floatx4*)(A + row * 128 + kk * 32 + q * 8);
                    floatx4 f0 = p[0], f1 = p[1];
                    ushort8 u;
                    u[0] = bf16bits(f0.x); u[1] = bf16bits(f0.y);
                    u[2] = bf16bits(f0.z); u[3] = bf16bits(f0.w);
                    u[4] = bf16bits(f1.x); u[5] = bf16bits(f1.y);
                    u[6] = bf16bits(f1.z); u[7] = bf16bits(f1.w);
                    a = __builtin_bit_cast(bf16x8, u);
                }
                afrag[mi] = a;
            }
#pragma unroll
            for (int mi = 0; mi < 4; ++mi)
#pragma unroll
                for (int ni = 0; ni < 4; ++ni)
                    acc[mi][ni] = __builtin_amdgcn_mfma_f32_16x16x32_bf16(afrag[mi], bfrag[ni][kk], acc[mi][ni], 0, 0, 0);
        }
    }
#pragma unroll
    for (int mi = 0; mi < 4; ++mi)
#pragma unroll
        for (int rr = 0; rr < 4; ++rr) {
            int row = m0 + mi * 16 + q * 4 + rr;
            if (row < M) {
#pragma unroll
                for (int ni = 0; ni < 4; ++ni)
                    C[row * 256 + n0 + ni * 16 + r] = bf16bits(acc[mi][ni][rr]);
            }
        }
}

// ---------- FUSED attention H=4 + projection (gemm2): 8 dsts/block, 1 wave/dst ----------
// Phase 1: per-wave attention over incoming edges -> x1 row (bf16) in LDS.
// Phase 2: waves 0-3 run the exact gemm2 MFMA tile (A rows = 8 LDS rows, B = W2t).
// Measured: fusion saves ~8us (R6); 8-edge unroll NEUTRAL-to-worse (R7) -> keep 4-edge loop.
__global__ __launch_bounds__(512) void attn4proj_kernel(const unsigned short* __restrict__ ft,
                                                        const int* __restrict__ cnt,
                                                        const unsigned short* __restrict__ bucket,
                                                        const unsigned short* __restrict__ W2t,
                                                        unsigned short* __restrict__ ft2) {
    __shared__ unsigned short x1t[8][256];
    int w    = threadIdx.x >> 6;   // dst slot 0..7
    int lane = threadIdx.x & 63;
    int dstv = blockIdx.x * 8 + w;
    floatx4 hd = unpack4(*(const uint2*)(ft + dstv * 256 + lane * 4));
    int deg  = min(cnt[dstv], BCAP);
    int base = dstv * BCAP;
    float l = 0.f;
    floatx4 acc = {0.f, 0.f, 0.f, 0.f};
    int i0 = 0;
    for (; i0 + 4 <= deg; i0 += 4) {
        int sn0 = bucket[base + i0],     sn1 = bucket[base + i0 + 1];
        int sn2 = bucket[base + i0 + 2], sn3 = bucket[base + i0 + 3];
        uint2 r0 = *(const uint2*)(ft + sn0 * 256 + lane * 4);
        uint2 r1 = *(const uint2*)(ft + sn1 * 256 + lane * 4);
        uint2 r2 = *(const uint2*)(ft + sn2 * 256 + lane * 4);
        uint2 r3 = *(const uint2*)(ft + sn3 * 256 + lane * 4);
        floatx4 h0 = unpack4(r0), h1 = unpack4(r1), h2 = unpack4(r2), h3 = unpack4(r3);
        float p0 = h0.x * hd.x + h0.y * hd.y + h0.z * hd.z + h0.w * hd.w;
        float p1 = h1.x * hd.x + h1.y * hd.y + h1.z * hd.z + h1.w * hd.w;
        float p2 = h2.x * hd.x + h2.y * hd.y + h2.z * hd.z + h2.w * hd.w;
        float p3 = h3.x * hd.x + h3.y * hd.y + h3.z * hd.z + h3.w * hd.w;
        p0 += __shfl_xor(p0, 1); p1 += __shfl_xor(p1, 1); p2 += __shfl_xor(p2, 1); p3 += __shfl_xor(p3, 1);
        p0 += __shfl_xor(p0, 2); p1 += __shfl_xor(p1, 2); p2 += __shfl_xor(p2, 2); p3 += __shfl_xor(p3, 2);
        p0 += __shfl_xor(p0, 4); p1 += __shfl_xor(p1, 4); p2 += __shfl_xor(p2, 4); p3 += __shfl_xor(p3, 4);
        p0 += __shfl_xor(p0, 8); p1 += __shfl_xor(p1, 8); p2 += __shfl_xor(p2, 8); p3 += __shfl_xor(p3, 8);
        float w0 = __expf(p0 * 0.125f);
        float w1 = __expf(p1 * 0.125f);
        float w2 = __expf(p2 * 0.125f);
        float w3 = __expf(p3 * 0.125f);
        l += (w0 + w1) + (w2 + w3);
        acc.x += w0 * h0.x + w1 * h1.x + w2 * h2.x + w3 * h3.x;
        acc.y += w0 * h0.y + w1 * h1.y + w2 * h2.y + w3 * h3.y;
        acc.z += w0 * h0.z + w1 * h1.z + w2 * h2.z + w3 * h3.z;
        acc.w += w0 * h0.w + w1 * h1.w + w2 * h2.w + w3 * h3.w;
    }
    for (; i0 < deg; ++i0) {
        int sn = bucket[base + i0];
        floatx4 hs = unpack4(*(const uint2*)(ft + sn * 256 + lane * 4));
        float p = hs.x * hd.x + hs.y * hd.y + hs.z * hd.z + hs.w * hd.w;
        p += __shfl_xor(p, 1); p += __shfl_xor(p, 2);
        p += __shfl_xor(p, 4); p += __shfl_xor(p, 8);
        float wgt = __expf(p * 0.125f);
        l += wgt;
        acc.x += wgt * hs.x; acc.y += wgt * hs.y;
        acc.z += wgt * hs.z; acc.w += wgt * hs.w;
    }
    float inv = (l > 0.f) ? 1.f / l : 0.f;
    // x1 row (relu, bf16) -> LDS. lanes stride 8B -> 2-way bank alias (free).
    unsigned* xr = (unsigned*)&x1t[w][lane * 4];
    xr[0] = pack2(fmaxf(acc.x * inv, 0.f), fmaxf(acc.y * inv, 0.f));
    xr[1] = pack2(fmaxf(acc.z * inv, 0.f), fmaxf(acc.w * inv, 0.f));
    __syncthreads();
    // Phase 2: projection, identical MFMA structure to gemm2 (n0 = w*16)
    if (w < 4) {
        int q = lane >> 4, r = lane & 15;
        floatx4 pacc = {0.f, 0.f, 0.f, 0.f};
#pragma unroll
        for (int kk = 0; kk < 8; ++kk) {
            bf16x8 bfrag = *(const bf16x8*)(W2t + (w * 16 + r) * 256 + kk * 32 + q * 8);
            bf16x8 afrag = {};
            if (r < 8) afrag = *(const bf16x8*)(&x1t[r][kk * 32 + q * 8]);
            pacc = __builtin_amdgcn_mfma_f32_16x16x32_bf16(afrag, bfrag, pacc, 0, 0, 0);
        }
#pragma unroll
        for (int rr = 0; rr < 4; ++rr) {
            int row = q * 4 + rr;
            if (row < 8)
                ft2[(blockIdx.x * 8 + row) * 64 + w * 16 + r] = bf16bits(pacc[rr]);
        }
    }
}

// ---------- attention H=1 (proven, R1-measured): wave=dst, 4 groups, unroll-2 -> x2 f32 ----------
// NOTE: do NOT replace the x2 store with atomicAdd pooling — measured +38us regression (R4):
// device-scope f32 atomics write through to HBM (16B/atomic) and serialize at ~156-way/address.
__global__ __launch_bounds__(256) void attn_h1_kernel(const unsigned short* __restrict__ ft,
                                                      const int* __restrict__ cnt,
                                                      const unsigned short* __restrict__ bucket,
                                                      float* __restrict__ out) {
    int dstv = blockIdx.x * 4 + (threadIdx.x >> 6);
    int lane = threadIdx.x & 63;
    int g = lane >> 4, s = lane & 15;
    int hbase = s * 4;
    floatx4 hd = unpack4(*(const uint2*)(ft + dstv * 64 + hbase));
    int deg  = min(cnt[dstv], BCAP);
    int base = dstv * BCAP;
    float l = 0.f;
    floatx4 acc = {0.f, 0.f, 0.f, 0.f};
    int i0 = 0;
    for (; i0 + 8 <= deg; i0 += 8) {
        int ia = i0 + g, ib = i0 + 4 + g;
        int sa = bucket[base + ia], sb = bucket[base + ib];
        uint2 ra = *(const uint2*)(ft + sa * 64 + hbase);
        uint2 rb = *(const uint2*)(ft + sb * 64 + hbase);
        floatx4 ha = unpack4(ra), hb = unpack4(rb);
        float pa = ha.x * hd.x + ha.y * hd.y + ha.z * hd.z + ha.w * hd.w;
        float pb = hb.x * hd.x + hb.y * hd.y + hb.z * hd.z + hb.w * hd.w;
        pa += __shfl_xor(pa, 1); pb += __shfl_xor(pb, 1);
        pa += __shfl_xor(pa, 2); pb += __shfl_xor(pb, 2);
        pa += __shfl_xor(pa, 4); pb += __shfl_xor(pb, 4);
        pa += __shfl_xor(pa, 8); pb += __shfl_xor(pb, 8);
        float wa = __expf(pa * 0.125f);
        float wb = __expf(pb * 0.125f);
        l += wa + wb;
        acc.x += wa * ha.x + wb * hb.x;
        acc.y += wa * ha.y + wb * hb.y;
        acc.z += wa * ha.z + wb * hb.z;
        acc.w += wa * ha.w + wb * hb.w;
    }
    for (; i0 < deg; i0 += 4) {
        int i = i0 + g;
        bool valid = (i < deg);
        int sn = valid ? bucket[base + i] : 0;
        floatx4 hs = unpack4(*(const uint2*)(ft + sn * 64 + hbase));
        float p = hs.x * hd.x + hs.y * hd.y + hs.z * hd.z + hs.w * hd.w;
        p += __shfl_xor(p, 1); p += __shfl_xor(p, 2);
        p += __shfl_xor(p, 4); p += __shfl_xor(p, 8);
        float wgt = valid ? __expf(p * 0.125f) : 0.f;
        l += wgt;
        acc.x += wgt * hs.x; acc.y += wgt * hs.y;
        acc.z += wgt * hs.z; acc.w += wgt * hs.w;
    }
    l += __shfl_xor(l, 16); l += __shfl_xor(l, 32);
    acc.x += __shfl_xor(acc.x, 16); acc.x += __shfl_xor(acc.x, 32);
    acc.y += __shfl_xor(acc.y, 16); acc.y += __shfl_xor(acc.y, 32);
    acc.z += __shfl_xor(acc.z, 16); acc.z += __shfl_xor(acc.z, 32);
    acc.w += __shfl_xor(acc.w, 16); acc.w += __shfl_xor(acc.w, 32);
    float inv = (l > 0.f) ? 1.f / l : 0.f;
    if (g == 0) {
        floatx4 o = {fmaxf(acc.x * inv, 0.f), fmaxf(acc.y * inv, 0.f),
                     fmaxf(acc.z * inv, 0.f), fmaxf(acc.w * inv, 0.f)};
        *(floatx4*)(out + dstv * 64 + hbase) = o;
    }
}

// ---------- fused mean-pool + classifier (proven): 1 block / graph ----------
__global__ __launch_bounds__(256) void poolclass_kernel(const float* __restrict__ x,
                                                        const int* __restrict__ gid,
                                                        const float* __restrict__ Wc,
                                                        const float* __restrict__ bc,
                                                        void* out, const int* flag) {
    __shared__ int s_lo, s_hi;
    __shared__ float part[4][64];
    int g = blockIdx.x;
    int tid = threadIdx.x;
    if (tid == 0) {
        int lo = 0, hi = N_NODES;
        while (lo < hi) { int m = (lo + hi) >> 1; if (gid[m] < g) lo = m + 1; else hi = m; }
        s_lo = lo;
        int lo2 = lo, hi2 = N_NODES;
        while (lo2 < hi2) { int m = (lo2 + hi2) >> 1; if (gid[m] < g + 1) lo2 = m + 1; else hi2 = m; }
        s_hi = lo2;
    }
    __syncthreads();
    int lo = s_lo, hi = s_hi;
    int d = tid & 63, w = tid >> 6;
    float sum = 0.f;
    for (int n = lo + w; n < hi; n += 4) sum += x[n * 64 + d];
    part[w][d] = sum;
    __syncthreads();
    if (w == 0) {
        float tot = part[0][d] + part[1][d] + part[2][d] + part[3][d];
        int cntg = hi - lo;
        float mean = (cntg > 0) ? tot / (float)cntg : 0.f;
        for (int cls = 0; cls < N_CLASSES; ++cls) {
            float p = mean * Wc[d * N_CLASSES + cls];
#pragma unroll
            for (int o = 1; o < 64; o <<= 1) p += __shfl_xor(p, o);
            if (d == 0) {
                float r = p + bc[cls];
                if (*flag) ((__hip_bfloat16*)out)[g * N_CLASSES + cls] = __float2bfloat16(r);
                else       ((float*)out)[g * N_CLASSES + cls] = r;
            }
        }
    }
}

static inline size_t align256(size_t x) { return (x + 255) & ~size_t(255); }

extern "C" void kernel_launch(void* const* d_in, const int* in_sizes, int n_in,
                              void* d_out, int out_size, void* d_ws, size_t ws_size,
                              hipStream_t stream) {
    const void* h_raw  = d_in[0];
    const int*  src    = (const int*)d_in[1];
    const int*  dst    = (const int*)d_in[2];
    const int*  gid    = (const int*)d_in[3];
    const void* W1_raw = d_in[4];
    const void* W2_raw = d_in[5];
    const void* Wc_raw = d_in[6];
    const void* bc_raw = d_in[7];

    // ---- workspace layout (bucket now ushort: 5.12MB) ----
    char* w = (char*)d_ws;
    int*  flag     = (int*)w;                      w += 256;
    int*  cnt      = (int*)w;                      w += align256(N_NODES * 4);
    unsigned short* bucket = (unsigned short*)w;   w += align256((size_t)N_NODES * BCAP * 2);
    unsigned short* W1t = (unsigned short*)w;      w += align256(256 * 128 * 2);
    unsigned short* W2t = (unsigned short*)w;      w += align256(64 * 256 * 2);
    float* Wcf     = (float*)w;                    w += align256(HID * N_CLASSES * 4);
    float* bcf     = (float*)w;                    w += 256;
    unsigned short* ft1  = (unsigned short*)w;     w += align256((size_t)N_NODES * 256 * 2);
    unsigned short* ft2  = (unsigned short*)w;     w += align256((size_t)N_NODES * HID * 2);
    float* x2      = (float*)w;                    w += align256((size_t)N_NODES * HID * 4);

    // 1) zero cnt via DMA memset node
    hipMemsetAsync(cnt, 0, N_NODES * sizeof(int), stream);

    // 2) fused prep: convW+detect (195) + bucket-fill (1250)
    hipLaunchKernelGGL(prep_kernel, dim3(195 + 1250), dim3(256), 0, stream,
                       W1_raw, W2_raw, Wc_raw, bc_raw, W1t, W2t, Wcf, bcf,
                       src, dst, cnt, bucket,
                       (const unsigned int*)h_raw, flag);

    // 3) layer 1 GEMM (MFMA), reads h directly in either dtype
    hipLaunchKernelGGL(gemm1_kernel, dim3((N_NODES + 63) / 64), dim3(256), 0, stream,
                       h_raw, W1t, ft1, N_NODES, flag);

    // 4) FUSED attention layer 1 + W2 projection -> ft2  [8 dsts/block, 4-edge loop]
    hipLaunchKernelGGL(attn4proj_kernel, dim3(N_NODES / 8), dim3(512), 0, stream,
                       ft1, cnt, bucket, W2t, ft2);

    // 5) attention layer 2 -> x2 (f32, coalesced store — NOT atomics)
    hipLaunchKernelGGL(attn_h1_kernel, dim3(N_NODES / 4), dim3(256), 0, stream,
                       ft2, cnt, bucket, x2);

    // 6) fused mean-pool + classifier -> d_out
    hipLaunchKernelGGL(poolclass_kernel, dim3(NUM_GRAPHS), dim3(256), 0, stream,
                       x2, gid, Wcf, bcf, d_out, flag);
}